// Round 1
// baseline (169.172 us; speedup 1.0000x reference)
//
#include <hip/hip_runtime.h>
#include <hip/hip_bf16.h>

#define NB 256      // batch == queries == classes
#define NL 256      // clips
#define SCALE 100.0f  // 1/TAU

typedef __attribute__((ext_vector_type(4))) unsigned int u32x4;
typedef __attribute__((ext_vector_type(8))) __bf16 bfrag8;
typedef __attribute__((ext_vector_type(4))) float f32x4;

static __device__ __forceinline__ unsigned int pack2bf(float a, float b) {
  union { float f; unsigned int u; } ua, ub;
  ua.f = a; ub.f = b;
  unsigned int ra = (ua.u + 0x7FFFu + ((ua.u >> 16) & 1u)) >> 16;
  unsigned int rb = (ub.u + 0x7FFFu + ((ub.u >> 16) & 1u)) & 0xFFFF0000u;
  return ra | rb;
}

// ---------------------------------------------------------------------------
// Kernel 1: softmax over l (axis=1) of src[b,l,i], write bf16 transposed as
// dst[i][b][l] (row-major, l contiguous).  One block per (b, which-input).
// thread = i  -> global reads coalesced (1KB per wave instr); writes are
// per-thread-contiguous 512B rows (uint4), L2 write-combines to full lines.
// Target additionally multiplied by mask[i,l] AFTER softmax (reference semantics).
// ---------------------------------------------------------------------------
__global__ __launch_bounds__(256) void softmax_t(
    const float* __restrict__ x, const float* __restrict__ tgt,
    unsigned int* __restrict__ xsT, unsigned int* __restrict__ tsT,
    const int* __restrict__ mask)
{
  const int b = blockIdx.x;
  const bool is_t = (blockIdx.y != 0);
  const int i = threadIdx.x;
  const float* src = (is_t ? tgt : x) + (size_t)b * (NL * NB) + i;
  unsigned int* dst = (is_t ? tsT : xsT) + ((size_t)i * NB + b) * (NL / 2);

  // pass 1: sum of exp (no max subtraction: inputs ~N(0,1), fp32-safe)
  float s0 = 0.f, s1 = 0.f, s2 = 0.f, s3 = 0.f;
  #pragma unroll 4
  for (int l = 0; l < NL; l += 4) {
    s0 += __expf(src[(l + 0) * NB]);
    s1 += __expf(src[(l + 1) * NB]);
    s2 += __expf(src[(l + 2) * NB]);
    s3 += __expf(src[(l + 3) * NB]);
  }
  const float inv = 1.0f / (s0 + s1 + s2 + s3);

  // pass 2: normalize, (mask), pack bf16, store 16B at a time
  #pragma unroll 4
  for (int lg = 0; lg < NL / 8; ++lg) {
    float v[8];
    #pragma unroll
    for (int k = 0; k < 8; ++k)
      v[k] = __expf(src[(lg * 8 + k) * NB]) * inv;
    if (is_t) {
      const u32x4* mrow = reinterpret_cast<const u32x4*>(mask + i * NL + lg * 8);
      u32x4 m0 = mrow[0], m1 = mrow[1];
      if ((int)m0.x <= 0) v[0] = 0.f;
      if ((int)m0.y <= 0) v[1] = 0.f;
      if ((int)m0.z <= 0) v[2] = 0.f;
      if ((int)m0.w <= 0) v[3] = 0.f;
      if ((int)m1.x <= 0) v[4] = 0.f;
      if ((int)m1.y <= 0) v[5] = 0.f;
      if ((int)m1.z <= 0) v[6] = 0.f;
      if ((int)m1.w <= 0) v[7] = 0.f;
    }
    u32x4 o;
    o.x = pack2bf(v[0], v[1]);
    o.y = pack2bf(v[2], v[3]);
    o.z = pack2bf(v[4], v[5]);
    o.w = pack2bf(v[6], v[7]);
    *reinterpret_cast<u32x4*>(dst + lg * 4) = o;
  }
}

// ---------------------------------------------------------------------------
// Kernel 2: per-i NT GEMM sim[j,c] = sum_l XsT[i][j][l]*TsT[i][c][l], fused
// log-softmax over c and label-weighted diagonal pick, atomicAdd scalar loss.
// Block: (jt, i); 4 waves; output tile 64j x 256c (wave w owns c in [64w,64w+64)).
// K=256 in 4 chunks of 64; LDS tiles XOR-swizzled (T2) against the 128B-stride
// bank conflict.  mfma_f32_16x16x32_bf16, NT operand pattern (m89/m90-verified).
// ---------------------------------------------------------------------------
__global__ __launch_bounds__(256) void gemm_lse(
    const unsigned short* __restrict__ xsT,
    const unsigned short* __restrict__ tsT,
    const int* __restrict__ label_mat,
    float* __restrict__ out)
{
  const int i  = blockIdx.y;
  const int jt = blockIdx.x;
  const int t  = threadIdx.x;
  const int w  = t >> 6;
  const int lane = t & 63;

  __shared__ __align__(16) unsigned char As[64 * 128];    // [64 j][64 l] bf16, swizzled
  __shared__ __align__(16) unsigned char Bs[256 * 128];   // [256 c][64 l] bf16, swizzled
  __shared__ float s_rmax[4][64];
  __shared__ float s_rsum[4][64];
  __shared__ float s_diag[64];

  const unsigned short* Ag = xsT + ((size_t)i * NB + jt * 64) * NL;  // rows j
  const unsigned short* Bg = tsT + (size_t)i * NB * NL;              // rows c

  u32x4 areg[2], breg[8];

  auto load_chunk = [&](int kc) {
    const int kofs = kc * 64;
    #pragma unroll
    for (int r = 0; r < 2; ++r) {
      int idx = t + r * 256;               // 0..511 -> A: 64 rows x 8 chunks
      int row = idx >> 3, ch = idx & 7;
      areg[r] = *reinterpret_cast<const u32x4*>(Ag + (size_t)row * NL + kofs + ch * 8);
    }
    #pragma unroll
    for (int r = 0; r < 8; ++r) {
      int idx = t + r * 256;               // 0..2047 -> B: 256 rows x 8 chunks
      int row = idx >> 3, ch = idx & 7;
      breg[r] = *reinterpret_cast<const u32x4*>(Bg + (size_t)row * NL + kofs + ch * 8);
    }
  };
  auto store_chunk = [&]() {
    #pragma unroll
    for (int r = 0; r < 2; ++r) {
      int idx = t + r * 256;
      int row = idx >> 3, ch = idx & 7;
      *reinterpret_cast<u32x4*>(&As[row * 128 + ((ch ^ (row & 7)) << 4)]) = areg[r];
    }
    #pragma unroll
    for (int r = 0; r < 8; ++r) {
      int idx = t + r * 256;
      int row = idx >> 3, ch = idx & 7;
      *reinterpret_cast<u32x4*>(&Bs[row * 128 + ((ch ^ (row & 7)) << 4)]) = breg[r];
    }
  };

  f32x4 acc[4][4];
  #pragma unroll
  for (int a = 0; a < 4; ++a)
    #pragma unroll
    for (int c = 0; c < 4; ++c) acc[a][c] = f32x4{0.f, 0.f, 0.f, 0.f};

  load_chunk(0);
  #pragma unroll
  for (int kc = 0; kc < 4; ++kc) {
    store_chunk();
    __syncthreads();
    if (kc < 3) load_chunk(kc + 1);
    #pragma unroll
    for (int kk = 0; kk < 2; ++kk) {
      const int bofs = kk * 64 + ((lane >> 4) << 4);  // byte offset within row
      bfrag8 af[4], bfr[4];
      #pragma unroll
      for (int jf = 0; jf < 4; ++jf) {
        int row = jf * 16 + (lane & 15);
        af[jf] = *reinterpret_cast<const bfrag8*>(
            &As[row * 128 + (((bofs >> 4) ^ (row & 7)) << 4)]);
      }
      #pragma unroll
      for (int cf = 0; cf < 4; ++cf) {
        int row = w * 64 + cf * 16 + (lane & 15);
        bfr[cf] = *reinterpret_cast<const bfrag8*>(
            &Bs[row * 128 + (((bofs >> 4) ^ (row & 7)) << 4)]);
      }
      #pragma unroll
      for (int jf = 0; jf < 4; ++jf)
        #pragma unroll
        for (int cf = 0; cf < 4; ++cf)
          acc[jf][cf] = __builtin_amdgcn_mfma_f32_16x16x32_bf16(
              af[jf], bfr[cf], acc[jf][cf], 0, 0, 0);
    }
    __syncthreads();
  }

  // ---- epilogue: logits = 100*sim; per-row (j) logsumexp over c; diag pick ----
  #pragma unroll
  for (int jf = 0; jf < 4; ++jf)
    #pragma unroll
    for (int cf = 0; cf < 4; ++cf) acc[jf][cf] *= SCALE;

  const int rg = (lane >> 4) << 2;  // this lane holds rows jf*16 + rg + reg

  float rmax[4][4];
  #pragma unroll
  for (int jf = 0; jf < 4; ++jf) {
    #pragma unroll
    for (int reg = 0; reg < 4; ++reg) {
      float m = fmaxf(fmaxf(acc[jf][0][reg], acc[jf][1][reg]),
                      fmaxf(acc[jf][2][reg], acc[jf][3][reg]));
      #pragma unroll
      for (int off = 1; off < 16; off <<= 1) m = fmaxf(m, __shfl_xor(m, off, 64));
      rmax[jf][reg] = m;
    }
  }
  if ((lane & 15) == 0) {
    #pragma unroll
    for (int jf = 0; jf < 4; ++jf)
      #pragma unroll
      for (int reg = 0; reg < 4; ++reg)
        s_rmax[w][jf * 16 + rg + reg] = rmax[jf][reg];
  }
  __syncthreads();

  float gmax[4][4];
  #pragma unroll
  for (int jf = 0; jf < 4; ++jf)
    #pragma unroll
    for (int reg = 0; reg < 4; ++reg) {
      int row = jf * 16 + rg + reg;
      gmax[jf][reg] = fmaxf(fmaxf(s_rmax[0][row], s_rmax[1][row]),
                            fmaxf(s_rmax[2][row], s_rmax[3][row]));
    }

  #pragma unroll
  for (int jf = 0; jf < 4; ++jf) {
    #pragma unroll
    for (int reg = 0; reg < 4; ++reg) {
      float s = 0.f;
      #pragma unroll
      for (int cf = 0; cf < 4; ++cf) s += __expf(acc[jf][cf][reg] - gmax[jf][reg]);
      #pragma unroll
      for (int off = 1; off < 16; off <<= 1) s += __shfl_xor(s, off, 64);
      if ((lane & 15) == 0) s_rsum[w][jf * 16 + rg + reg] = s;
    }
  }
  // diagonal element c == i lives in wave i>>6, frag (i>>4)&3, lanes with lane&15 == i&15
  if (w == (i >> 6) && (lane & 15) == (i & 15)) {
    const int cfd = (i >> 4) & 3;
    #pragma unroll
    for (int jf = 0; jf < 4; ++jf)
      #pragma unroll
      for (int reg = 0; reg < 4; ++reg)
        s_diag[jf * 16 + rg + reg] = acc[jf][cfd][reg];
  }
  __syncthreads();

  float contrib = 0.f;
  if (t < 64) {
    const int row = t;
    float gm = fmaxf(fmaxf(s_rmax[0][row], s_rmax[1][row]),
                     fmaxf(s_rmax[2][row], s_rmax[3][row]));
    float tot = s_rsum[0][row] + s_rsum[1][row] + s_rsum[2][row] + s_rsum[3][row];
    float lse = __logf(tot) + gm;
    float lbl = (float)label_mat[i * NB + jt * 64 + row];
    contrib = lbl * (s_diag[row] - lse);
  }
  #pragma unroll
  for (int off = 32; off >= 1; off >>= 1) contrib += __shfl_down(contrib, off, 64);
  if (t == 0) atomicAdd(out, contrib * (-1.0f / 256.0f));
}

extern "C" void kernel_launch(void* const* d_in, const int* in_sizes, int n_in,
                              void* d_out, int out_size, void* d_ws, size_t ws_size,
                              hipStream_t stream) {
  const float* x   = (const float*)d_in[0];
  const float* tgt = (const float*)d_in[1];
  const int* mask  = (const int*)d_in[2];
  // d_in[3] = query_labels (unused by the reference computation)
  const int* label_mat = (const int*)d_in[4];
  float* out = (float*)d_out;

  unsigned int* xsT = (unsigned int*)d_ws;                       // 32 MiB bf16 [i][j][l]
  unsigned int* tsT = xsT + (size_t)NB * NB * NL / 2;            // 32 MiB bf16 [i][c][l]

  hipMemsetAsync(out, 0, sizeof(float), stream);
  softmax_t<<<dim3(NB, 2), 256, 0, stream>>>(x, tgt, xsT, tsT, mask);
  gemm_lse<<<dim3(4, NB), 256, 0, stream>>>((const unsigned short*)xsT,
                                            (const unsigned short*)tsT,
                                            label_mat, out);
}

// Round 2
// 153.078 us; speedup vs baseline: 1.1051x; 1.1051x over previous
//
#include <hip/hip_runtime.h>
#include <hip/hip_bf16.h>

#define NB 256      // batch == queries == classes
#define NL 256      // clips
#define SCALE 100.0f  // 1/TAU

typedef __attribute__((ext_vector_type(4))) unsigned int u32x4;
typedef __attribute__((ext_vector_type(8))) __bf16 bfrag8;
typedef __attribute__((ext_vector_type(4))) float f32x4;

static __device__ __forceinline__ unsigned int pack2bf(float a, float b) {
  union { float f; unsigned int u; } ua, ub;
  ua.f = a; ub.f = b;
  unsigned int ra = (ua.u + 0x7FFFu + ((ua.u >> 16) & 1u)) >> 16;
  unsigned int rb = (ub.u + 0x7FFFu + ((ub.u >> 16) & 1u)) & 0xFFFF0000u;
  return ra | rb;
}

// ---------------------------------------------------------------------------
// Kernel 1: softmax over l (axis=1) of src[b,l,i], write bf16 transposed as
// dst[i][b][l].  Block = 1024 threads: i = tid&255 (coalesced reads), h =
// tid>>8 picks a 64-long l-quarter; LDS combines the 4 partial exp-sums.
// Each thread emits exactly one 128B line (64 bf16) as a burst of 8x16B
// stores -> full-line writes, no partial-line RMW amplification.
// 512 blocks x 16 waves = 32 waves/CU (full occupancy).
// ---------------------------------------------------------------------------
__global__ __launch_bounds__(1024, 4) void softmax_t(
    const float* __restrict__ x, const float* __restrict__ tgt,
    unsigned int* __restrict__ xsT, unsigned int* __restrict__ tsT,
    const int* __restrict__ mask)
{
  const int b = blockIdx.x;
  const bool is_t = (blockIdx.y != 0);
  const int i = threadIdx.x & 255;
  const int h = threadIdx.x >> 8;  // l-quarter
  const float* src = (is_t ? tgt : x) + (size_t)b * (NL * NB) + (size_t)h * 64 * NB + i;
  unsigned int* dst = (is_t ? tsT : xsT) + ((size_t)i * NB + b) * (NL / 2) + h * 32;

  __shared__ float s_sum[4][256];

  // pass 1: partial sum of exp over this thread's 64 l's (inputs ~N(0,1), fp32-safe)
  float s = 0.f;
  #pragma unroll 8
  for (int l = 0; l < 64; ++l) s += __expf(src[(size_t)l * NB]);
  s_sum[h][i] = s;
  __syncthreads();
  const float inv = 1.0f / (s_sum[0][i] + s_sum[1][i] + s_sum[2][i] + s_sum[3][i]);

  // pass 2: recompute (L2-hot), normalize, (mask), pack bf16 into one 128B line
  u32x4 o[8];
  #pragma unroll
  for (int c = 0; c < 8; ++c) {
    float v[8];
    #pragma unroll
    for (int k = 0; k < 8; ++k)
      v[k] = __expf(src[(size_t)(c * 8 + k) * NB]) * inv;
    if (is_t) {
      const u32x4* mrow = reinterpret_cast<const u32x4*>(mask + i * NL + h * 64 + c * 8);
      u32x4 m0 = mrow[0], m1 = mrow[1];
      if ((int)m0.x <= 0) v[0] = 0.f;
      if ((int)m0.y <= 0) v[1] = 0.f;
      if ((int)m0.z <= 0) v[2] = 0.f;
      if ((int)m0.w <= 0) v[3] = 0.f;
      if ((int)m1.x <= 0) v[4] = 0.f;
      if ((int)m1.y <= 0) v[5] = 0.f;
      if ((int)m1.z <= 0) v[6] = 0.f;
      if ((int)m1.w <= 0) v[7] = 0.f;
    }
    o[c].x = pack2bf(v[0], v[1]);
    o[c].y = pack2bf(v[2], v[3]);
    o[c].z = pack2bf(v[4], v[5]);
    o[c].w = pack2bf(v[6], v[7]);
  }
  u32x4* dq = reinterpret_cast<u32x4*>(dst);
  #pragma unroll
  for (int c = 0; c < 8; ++c) dq[c] = o[c];
}

// ---------------------------------------------------------------------------
// Kernel 2: per-i NT GEMM sim[j,c] = sum_l XsT[i][j][l]*TsT[i][c][l], fused
// log-softmax over c + label-weighted diagonal pick, atomicAdd scalar loss.
// __launch_bounds__(256, 2): VGPR cap 256 -> live set (~180) fits, NO SPILLS
// (round-1 had VGPR=104 + 328 MB scratch writes).  LDS XOR-swizzled (T2).
// ---------------------------------------------------------------------------
__global__ __launch_bounds__(256, 2) void gemm_lse(
    const unsigned short* __restrict__ xsT,
    const unsigned short* __restrict__ tsT,
    const int* __restrict__ label_mat,
    float* __restrict__ out)
{
  const int i  = blockIdx.y;
  const int jt = blockIdx.x;
  const int t  = threadIdx.x;
  const int w  = t >> 6;
  const int lane = t & 63;

  __shared__ __align__(16) unsigned char As[64 * 128];    // [64 j][64 l] bf16, swizzled
  __shared__ __align__(16) unsigned char Bs[256 * 128];   // [256 c][64 l] bf16, swizzled
  __shared__ float s_rmax[4][64];
  __shared__ float s_rsum[4][64];
  __shared__ float s_diag[64];

  const unsigned short* Ag = xsT + ((size_t)i * NB + jt * 64) * NL;  // rows j
  const unsigned short* Bg = tsT + (size_t)i * NB * NL;              // rows c

  const int srow = t >> 3;       // staging row base (A: 0..31, B: 0..31)
  const int sch  = t & 7;        // staging 16B-chunk within row

  f32x4 acc[4][4];
  #pragma unroll
  for (int a = 0; a < 4; ++a)
    #pragma unroll
    for (int c = 0; c < 4; ++c) acc[a][c] = f32x4{0.f, 0.f, 0.f, 0.f};

  u32x4 areg[2], breg[8];

  // prologue: load chunk 0
  #pragma unroll
  for (int r = 0; r < 2; ++r)
    areg[r] = *reinterpret_cast<const u32x4*>(Ag + (size_t)(srow + r * 32) * NL + sch * 8);
  #pragma unroll
  for (int r = 0; r < 8; ++r)
    breg[r] = *reinterpret_cast<const u32x4*>(Bg + (size_t)(srow + r * 32) * NL + sch * 8);

  #pragma unroll
  for (int kc = 0; kc < 4; ++kc) {
    // store staged chunk (XOR-swizzled)
    #pragma unroll
    for (int r = 0; r < 2; ++r) {
      int row = srow + r * 32;
      *reinterpret_cast<u32x4*>(&As[row * 128 + ((sch ^ (row & 7)) << 4)]) = areg[r];
    }
    #pragma unroll
    for (int r = 0; r < 8; ++r) {
      int row = srow + r * 32;
      *reinterpret_cast<u32x4*>(&Bs[row * 128 + ((sch ^ (row & 7)) << 4)]) = breg[r];
    }
    __syncthreads();
    if (kc < 3) {
      const int kofs = (kc + 1) * 64;
      #pragma unroll
      for (int r = 0; r < 2; ++r)
        areg[r] = *reinterpret_cast<const u32x4*>(Ag + (size_t)(srow + r * 32) * NL + kofs + sch * 8);
      #pragma unroll
      for (int r = 0; r < 8; ++r)
        breg[r] = *reinterpret_cast<const u32x4*>(Bg + (size_t)(srow + r * 32) * NL + kofs + sch * 8);
    }
    #pragma unroll
    for (int kk = 0; kk < 2; ++kk) {
      const int co = kk * 4 + (lane >> 4);  // 16B chunk index within row
      bfrag8 af[4], bfr[4];
      #pragma unroll
      for (int jf = 0; jf < 4; ++jf) {
        int row = jf * 16 + (lane & 15);
        af[jf] = *reinterpret_cast<const bfrag8*>(&As[row * 128 + ((co ^ (row & 7)) << 4)]);
      }
      #pragma unroll
      for (int cf = 0; cf < 4; ++cf) {
        int row = w * 64 + cf * 16 + (lane & 15);
        bfr[cf] = *reinterpret_cast<const bfrag8*>(&Bs[row * 128 + ((co ^ (row & 7)) << 4)]);
      }
      #pragma unroll
      for (int jf = 0; jf < 4; ++jf)
        #pragma unroll
        for (int cf = 0; cf < 4; ++cf)
          acc[jf][cf] = __builtin_amdgcn_mfma_f32_16x16x32_bf16(
              af[jf], bfr[cf], acc[jf][cf], 0, 0, 0);
    }
    __syncthreads();
  }

  // ---- epilogue: logits = 100*sim; per-row (j) logsumexp over c; diag pick ----
  #pragma unroll
  for (int jf = 0; jf < 4; ++jf)
    #pragma unroll
    for (int cf = 0; cf < 4; ++cf) acc[jf][cf] *= SCALE;

  const int rg = (lane >> 4) << 2;  // this lane holds rows jf*16 + rg + reg

  #pragma unroll
  for (int jf = 0; jf < 4; ++jf) {
    #pragma unroll
    for (int reg = 0; reg < 4; ++reg) {
      float m = fmaxf(fmaxf(acc[jf][0][reg], acc[jf][1][reg]),
                      fmaxf(acc[jf][2][reg], acc[jf][3][reg]));
      #pragma unroll
      for (int off = 1; off < 16; off <<= 1) m = fmaxf(m, __shfl_xor(m, off, 64));
      if ((lane & 15) == 0) s_rmax[w][jf * 16 + rg + reg] = m;
    }
  }
  // diagonal element c == i lives in wave i>>6, frag (i>>4)&3, lanes lane&15 == i&15
  if (w == (i >> 6) && (lane & 15) == (i & 15)) {
    const int cfd = (i >> 4) & 3;
    #pragma unroll
    for (int jf = 0; jf < 4; ++jf)
      #pragma unroll
      for (int reg = 0; reg < 4; ++reg)
        s_diag[jf * 16 + rg + reg] = acc[jf][cfd][reg];
  }
  __syncthreads();

  #pragma unroll
  for (int jf = 0; jf < 4; ++jf) {
    #pragma unroll
    for (int reg = 0; reg < 4; ++reg) {
      int row = jf * 16 + rg + reg;
      float gm = fmaxf(fmaxf(s_rmax[0][row], s_rmax[1][row]),
                       fmaxf(s_rmax[2][row], s_rmax[3][row]));
      float sE = 0.f;
      #pragma unroll
      for (int cf = 0; cf < 4; ++cf) sE += __expf(acc[jf][cf][reg] - gm);
      #pragma unroll
      for (int off = 1; off < 16; off <<= 1) sE += __shfl_xor(sE, off, 64);
      if ((lane & 15) == 0) s_rsum[w][row] = sE;
    }
  }
  __syncthreads();

  float contrib = 0.f;
  if (t < 64) {
    const int row = t;
    float gm = fmaxf(fmaxf(s_rmax[0][row], s_rmax[1][row]),
                     fmaxf(s_rmax[2][row], s_rmax[3][row]));
    float tot = s_rsum[0][row] + s_rsum[1][row] + s_rsum[2][row] + s_rsum[3][row];
    float lse = __logf(tot) + gm;
    float lbl = (float)label_mat[i * NB + jt * 64 + row];
    contrib = lbl * (s_diag[row] - lse);
  }
  #pragma unroll
  for (int off = 32; off >= 1; off >>= 1) contrib += __shfl_down(contrib, off, 64);
  if (t == 0) atomicAdd(out, contrib * (-1.0f / 256.0f));
}

extern "C" void kernel_launch(void* const* d_in, const int* in_sizes, int n_in,
                              void* d_out, int out_size, void* d_ws, size_t ws_size,
                              hipStream_t stream) {
  const float* x   = (const float*)d_in[0];
  const float* tgt = (const float*)d_in[1];
  const int* mask  = (const int*)d_in[2];
  // d_in[3] = query_labels (unused by the reference computation)
  const int* label_mat = (const int*)d_in[4];
  float* out = (float*)d_out;

  unsigned int* xsT = (unsigned int*)d_ws;                       // 32 MiB bf16 [i][j][l]
  unsigned int* tsT = xsT + (size_t)NB * NB * NL / 2;            // 32 MiB bf16 [i][c][l]

  hipMemsetAsync(out, 0, sizeof(float), stream);
  softmax_t<<<dim3(NB, 2), 1024, 0, stream>>>(x, tgt, xsT, tsT, mask);
  gemm_lse<<<dim3(4, NB), 256, 0, stream>>>((const unsigned short*)xsT,
                                            (const unsigned short*)tsT,
                                            label_mat, out);
}

// Round 3
// 112.500 us; speedup vs baseline: 1.5038x; 1.3607x over previous
//
#include <hip/hip_runtime.h>
#include <hip/hip_bf16.h>

#define NB 256      // batch == queries == classes
#define NL 256      // clips
#define SCALE 100.0f  // 1/TAU

typedef __attribute__((ext_vector_type(4))) unsigned int u32x4;
typedef __attribute__((ext_vector_type(8))) __bf16 bfrag8;
typedef __attribute__((ext_vector_type(4))) float f32x4;

static __device__ __forceinline__ unsigned int pack2bf(float a, float b) {
  union { float f; unsigned int u; } ua, ub;
  ua.f = a; ub.f = b;
  unsigned int ra = (ua.u + 0x7FFFu + ((ua.u >> 16) & 1u)) >> 16;
  unsigned int rb = (ub.u + 0x7FFFu + ((ub.u >> 16) & 1u)) & 0xFFFF0000u;
  return ra | rb;
}

// ---------------------------------------------------------------------------
// Kernel 1: softmax over l (axis=1) of src[b,l,i], write bf16 transposed as
// dst[i][b][l].  Block = 1024 threads: i = tid&255 (coalesced reads), h =
// tid>>8 picks a 64-long l-quarter; LDS combines the 4 partial exp-sums.
// Each thread emits exactly one 128B line (64 bf16) as a burst of 8x16B
// stores -> full-line writes, no partial-line RMW amplification.
// ---------------------------------------------------------------------------
__global__ __launch_bounds__(1024, 4) void softmax_t(
    const float* __restrict__ x, const float* __restrict__ tgt,
    unsigned int* __restrict__ xsT, unsigned int* __restrict__ tsT,
    const int* __restrict__ mask)
{
  const int b = blockIdx.x;
  const bool is_t = (blockIdx.y != 0);
  const int i = threadIdx.x & 255;
  const int h = threadIdx.x >> 8;  // l-quarter
  const float* src = (is_t ? tgt : x) + (size_t)b * (NL * NB) + (size_t)h * 64 * NB + i;
  unsigned int* dst = (is_t ? tsT : xsT) + ((size_t)i * NB + b) * (NL / 2) + h * 32;

  __shared__ float s_sum[4][256];

  // pass 1: partial sum of exp over this thread's 64 l's (inputs ~N(0,1), fp32-safe)
  float s = 0.f;
  #pragma unroll 8
  for (int l = 0; l < 64; ++l) s += __expf(src[(size_t)l * NB]);
  s_sum[h][i] = s;
  __syncthreads();
  const float inv = 1.0f / (s_sum[0][i] + s_sum[1][i] + s_sum[2][i] + s_sum[3][i]);

  // pass 2: recompute (L2-hot), normalize, (mask), pack bf16 into one 128B line
  u32x4 o[8];
  #pragma unroll
  for (int c = 0; c < 8; ++c) {
    float v[8];
    #pragma unroll
    for (int k = 0; k < 8; ++k)
      v[k] = __expf(src[(size_t)(c * 8 + k) * NB]) * inv;
    if (is_t) {
      const u32x4* mrow = reinterpret_cast<const u32x4*>(mask + i * NL + h * 64 + c * 8);
      u32x4 m0 = mrow[0], m1 = mrow[1];
      if ((int)m0.x <= 0) v[0] = 0.f;
      if ((int)m0.y <= 0) v[1] = 0.f;
      if ((int)m0.z <= 0) v[2] = 0.f;
      if ((int)m0.w <= 0) v[3] = 0.f;
      if ((int)m1.x <= 0) v[4] = 0.f;
      if ((int)m1.y <= 0) v[5] = 0.f;
      if ((int)m1.z <= 0) v[6] = 0.f;
      if ((int)m1.w <= 0) v[7] = 0.f;
    }
    o[c].x = pack2bf(v[0], v[1]);
    o[c].y = pack2bf(v[2], v[3]);
    o[c].z = pack2bf(v[4], v[5]);
    o[c].w = pack2bf(v[6], v[7]);
  }
  u32x4* dq = reinterpret_cast<u32x4*>(dst);
  #pragma unroll
  for (int c = 0; c < 8; ++c) dq[c] = o[c];
}

// ---------------------------------------------------------------------------
// Kernel 2: per-i NT GEMM sim[j,c] = sum_l XsT[i][j][l]*TsT[i][c][l], fused
// log-softmax over c + label-weighted diagonal pick, atomicAdd scalar loss.
// CRITICAL (rule #20): no runtime indexing into acc[][] anywhere — the diag
// pick uses compile-time indices + predicated select.  Round 1/2 had
// acc[jf][cfd][reg] with runtime cfd -> whole acc array in scratch
// (VGPR=80, 324 MB spill writes, MfmaUtil 2.5%).
// ---------------------------------------------------------------------------
__global__ __launch_bounds__(256, 2) void gemm_lse(
    const unsigned short* __restrict__ xsT,
    const unsigned short* __restrict__ tsT,
    const int* __restrict__ label_mat,
    float* __restrict__ out)
{
  const int i  = blockIdx.y;
  const int jt = blockIdx.x;
  const int t  = threadIdx.x;
  const int w  = t >> 6;
  const int lane = t & 63;

  __shared__ __align__(16) unsigned char As[64 * 128];    // [64 j][64 l] bf16, swizzled
  __shared__ __align__(16) unsigned char Bs[256 * 128];   // [256 c][64 l] bf16, swizzled
  __shared__ float s_rmax[4][64];
  __shared__ float s_rsum[4][64];
  __shared__ float s_diag[64];

  const unsigned short* Ag = xsT + ((size_t)i * NB + jt * 64) * NL;  // rows j
  const unsigned short* Bg = tsT + (size_t)i * NB * NL;              // rows c

  const int srow = t >> 3;       // staging row base
  const int sch  = t & 7;        // staging 16B-chunk within row

  f32x4 acc[4][4];
  #pragma unroll
  for (int a = 0; a < 4; ++a)
    #pragma unroll
    for (int c = 0; c < 4; ++c) acc[a][c] = f32x4{0.f, 0.f, 0.f, 0.f};

  u32x4 areg[2], breg[8];

  // prologue: load chunk 0
  #pragma unroll
  for (int r = 0; r < 2; ++r)
    areg[r] = *reinterpret_cast<const u32x4*>(Ag + (size_t)(srow + r * 32) * NL + sch * 8);
  #pragma unroll
  for (int r = 0; r < 8; ++r)
    breg[r] = *reinterpret_cast<const u32x4*>(Bg + (size_t)(srow + r * 32) * NL + sch * 8);

  #pragma unroll
  for (int kc = 0; kc < 4; ++kc) {
    // store staged chunk (XOR-swizzled)
    #pragma unroll
    for (int r = 0; r < 2; ++r) {
      int row = srow + r * 32;
      *reinterpret_cast<u32x4*>(&As[row * 128 + ((sch ^ (row & 7)) << 4)]) = areg[r];
    }
    #pragma unroll
    for (int r = 0; r < 8; ++r) {
      int row = srow + r * 32;
      *reinterpret_cast<u32x4*>(&Bs[row * 128 + ((sch ^ (row & 7)) << 4)]) = breg[r];
    }
    __syncthreads();
    if (kc < 3) {
      const int kofs = (kc + 1) * 64;
      #pragma unroll
      for (int r = 0; r < 2; ++r)
        areg[r] = *reinterpret_cast<const u32x4*>(Ag + (size_t)(srow + r * 32) * NL + kofs + sch * 8);
      #pragma unroll
      for (int r = 0; r < 8; ++r)
        breg[r] = *reinterpret_cast<const u32x4*>(Bg + (size_t)(srow + r * 32) * NL + kofs + sch * 8);
    }
    #pragma unroll
    for (int kk = 0; kk < 2; ++kk) {
      const int co = kk * 4 + (lane >> 4);  // 16B chunk index within row
      bfrag8 af[4], bfr[4];
      #pragma unroll
      for (int jf = 0; jf < 4; ++jf) {
        int row = jf * 16 + (lane & 15);
        af[jf] = *reinterpret_cast<const bfrag8*>(&As[row * 128 + ((co ^ (row & 7)) << 4)]);
      }
      #pragma unroll
      for (int cf = 0; cf < 4; ++cf) {
        int row = w * 64 + cf * 16 + (lane & 15);
        bfr[cf] = *reinterpret_cast<const bfrag8*>(&Bs[row * 128 + ((co ^ (row & 7)) << 4)]);
      }
      #pragma unroll
      for (int jf = 0; jf < 4; ++jf)
        #pragma unroll
        for (int cf = 0; cf < 4; ++cf)
          acc[jf][cf] = __builtin_amdgcn_mfma_f32_16x16x32_bf16(
              af[jf], bfr[cf], acc[jf][cf], 0, 0, 0);
    }
    __syncthreads();
  }

  // ---- epilogue: logits = 100*sim; per-row (j) logsumexp over c; diag pick ----
  #pragma unroll
  for (int jf = 0; jf < 4; ++jf)
    #pragma unroll
    for (int cf = 0; cf < 4; ++cf) acc[jf][cf] *= SCALE;

  const int rg = (lane >> 4) << 2;  // this lane holds rows jf*16 + rg + reg

  #pragma unroll
  for (int jf = 0; jf < 4; ++jf) {
    #pragma unroll
    for (int reg = 0; reg < 4; ++reg) {
      float m = fmaxf(fmaxf(acc[jf][0][reg], acc[jf][1][reg]),
                      fmaxf(acc[jf][2][reg], acc[jf][3][reg]));
      #pragma unroll
      for (int off = 1; off < 16; off <<= 1) m = fmaxf(m, __shfl_xor(m, off, 64));
      if ((lane & 15) == 0) s_rmax[w][jf * 16 + rg + reg] = m;
    }
  }
  // diagonal element c == i: wave i>>6, frag (i>>4)&3, lanes lane&15 == i&15.
  // COMPILE-TIME indices only — predicated select over cf (rule #20).
  if (w == (i >> 6) && (lane & 15) == (i & 15)) {
    const int cfd = (i >> 4) & 3;
    #pragma unroll
    for (int jf = 0; jf < 4; ++jf) {
      #pragma unroll
      for (int reg = 0; reg < 4; ++reg) {
        float v = acc[jf][0][reg];
        #pragma unroll
        for (int cf = 1; cf < 4; ++cf)
          v = (cfd == cf) ? acc[jf][cf][reg] : v;
        s_diag[jf * 16 + rg + reg] = v;
      }
    }
  }
  __syncthreads();

  #pragma unroll
  for (int jf = 0; jf < 4; ++jf) {
    #pragma unroll
    for (int reg = 0; reg < 4; ++reg) {
      int row = jf * 16 + rg + reg;
      float gm = fmaxf(fmaxf(s_rmax[0][row], s_rmax[1][row]),
                       fmaxf(s_rmax[2][row], s_rmax[3][row]));
      float sE = 0.f;
      #pragma unroll
      for (int cf = 0; cf < 4; ++cf) sE += __expf(acc[jf][cf][reg] - gm);
      #pragma unroll
      for (int off = 1; off < 16; off <<= 1) sE += __shfl_xor(sE, off, 64);
      if ((lane & 15) == 0) s_rsum[w][row] = sE;
    }
  }
  __syncthreads();

  float contrib = 0.f;
  if (t < 64) {
    const int row = t;
    float gm = fmaxf(fmaxf(s_rmax[0][row], s_rmax[1][row]),
                     fmaxf(s_rmax[2][row], s_rmax[3][row]));
    float tot = s_rsum[0][row] + s_rsum[1][row] + s_rsum[2][row] + s_rsum[3][row];
    float lse = __logf(tot) + gm;
    float lbl = (float)label_mat[i * NB + jt * 64 + row];
    contrib = lbl * (s_diag[row] - lse);
  }
  #pragma unroll
  for (int off = 32; off >= 1; off >>= 1) contrib += __shfl_down(contrib, off, 64);
  if (t == 0) atomicAdd(out, contrib * (-1.0f / 256.0f));
}

extern "C" void kernel_launch(void* const* d_in, const int* in_sizes, int n_in,
                              void* d_out, int out_size, void* d_ws, size_t ws_size,
                              hipStream_t stream) {
  const float* x   = (const float*)d_in[0];
  const float* tgt = (const float*)d_in[1];
  const int* mask  = (const int*)d_in[2];
  // d_in[3] = query_labels (unused by the reference computation)
  const int* label_mat = (const int*)d_in[4];
  float* out = (float*)d_out;

  unsigned int* xsT = (unsigned int*)d_ws;                       // 32 MiB bf16 [i][j][l]
  unsigned int* tsT = xsT + (size_t)NB * NB * NL / 2;            // 32 MiB bf16 [i][c][l]

  hipMemsetAsync(out, 0, sizeof(float), stream);
  softmax_t<<<dim3(NB, 2), 1024, 0, stream>>>(x, tgt, xsT, tsT, mask);
  gemm_lse<<<dim3(4, NB), 256, 0, stream>>>((const unsigned short*)xsT,
                                            (const unsigned short*)tsT,
                                            label_mat, out);
}

// Round 4
// 91.824 us; speedup vs baseline: 1.8424x; 1.2252x over previous
//
#include <hip/hip_runtime.h>
#include <hip/hip_bf16.h>

#define NB 256      // batch == queries == classes
#define NL 256      // clips
#define SCALE 100.0f  // 1/TAU

typedef __attribute__((ext_vector_type(4))) unsigned int u32x4;
typedef __attribute__((ext_vector_type(8))) __bf16 bfrag8;
typedef __attribute__((ext_vector_type(4))) float f32x4;

static __device__ __forceinline__ unsigned int pack2bf(float a, float b) {
  union { float f; unsigned int u; } ua, ub;
  ua.f = a; ub.f = b;
  unsigned int ra = (ua.u + 0x7FFFu + ((ua.u >> 16) & 1u)) >> 16;
  unsigned int rb = (ub.u + 0x7FFFu + ((ub.u >> 16) & 1u)) & 0xFFFF0000u;
  return ra | rb;
}

// ---------------------------------------------------------------------------
// Kernel 1: softmax over l of src[b,l,i], write bf16 transposed dst[i][b][l].
// NO mask here (mask is applied in the GEMM: masking A == masking ts under
// the dot product, since m is per-(i,l)).
// Round-3 problem: direct transposed writes had 64 lanes hitting 64 distinct
// 512B-strided rows per store inst (64 lines/inst).  Now: stage each 64-l
// chunk in a 32KB XOR-swizzled LDS tile, write out with 8 lanes per row ->
// every 8-lane group emits one FULL 128B line (8 lines/inst, fully
// coalesced at line granularity).  36KB LDS -> 2 blocks/CU, 32 waves/CU.
// ---------------------------------------------------------------------------
__global__ __launch_bounds__(1024, 2) void softmax_t(
    const float* __restrict__ x, const float* __restrict__ tgt,
    unsigned int* __restrict__ xsT, unsigned int* __restrict__ tsT)
{
  const int b = blockIdx.x;
  const bool is_t = (blockIdx.y != 0);
  const int tid = threadIdx.x;
  const int i = tid & 255;
  const int h = tid >> 8;  // l-quarter for pass 1 / l-sixteenth group in pass 2
  const float* src = (is_t ? tgt : x) + (size_t)b * (NL * NB) + i;
  unsigned int* dstb = (is_t ? tsT : xsT);  // u32-indexed, layout [i][b][l/2]

  __shared__ float s_sum[4][256];
  __shared__ __align__(16) unsigned char stg[256 * 128];  // [i][64 l] bf16, swizzled

  // pass 1: partial sum of exp (inputs ~N(0,1): no max subtraction needed)
  float s = 0.f;
  #pragma unroll 8
  for (int k = 0; k < 64; ++k) s += __expf(src[(size_t)(h * 64 + k) * NB]);
  s_sum[h][i] = s;
  __syncthreads();
  const float inv = 1.0f / (s_sum[0][i] + s_sum[1][i] + s_sum[2][i] + s_sum[3][i]);

  const int r0 = tid >> 3;  // writer rows r0 and r0+128
  const int c  = tid & 7;   // writer 16B chunk within 128B row-segment

  for (int lc = 0; lc < 4; ++lc) {
    // compute 16 normalized values for (i, l = lc*64 + h*16 + k); L2-hot re-read
    float v[16];
    #pragma unroll
    for (int k = 0; k < 16; ++k)
      v[k] = __expf(src[(size_t)(lc * 64 + h * 16 + k) * NB]) * inv;
    u32x4 p0, p1;
    p0.x = pack2bf(v[0], v[1]);   p0.y = pack2bf(v[2], v[3]);
    p0.z = pack2bf(v[4], v[5]);   p0.w = pack2bf(v[6], v[7]);
    p1.x = pack2bf(v[8], v[9]);   p1.y = pack2bf(v[10], v[11]);
    p1.z = pack2bf(v[12], v[13]); p1.w = pack2bf(v[14], v[15]);
    // stage: row i, chunks h*2, h*2+1, XOR-swizzled by i&7
    *reinterpret_cast<u32x4*>(&stg[i * 128 + (((h * 2 + 0) ^ (i & 7)) << 4)]) = p0;
    *reinterpret_cast<u32x4*>(&stg[i * 128 + (((h * 2 + 1) ^ (i & 7)) << 4)]) = p1;
    __syncthreads();
    // write out: 256 rows x 128B; 8 lanes per row -> one full line per group
    u32x4 q0 = *reinterpret_cast<const u32x4*>(&stg[r0 * 128 + ((c ^ (r0 & 7)) << 4)]);
    u32x4 q1 = *reinterpret_cast<const u32x4*>(&stg[(r0 + 128) * 128 + ((c ^ (r0 & 7)) << 4)]);
    *reinterpret_cast<u32x4*>(dstb + ((size_t)r0 * 256 + b) * 128 + lc * 32 + c * 4) = q0;
    *reinterpret_cast<u32x4*>(dstb + ((size_t)(r0 + 128) * 256 + b) * 128 + lc * 32 + c * 4) = q1;
    __syncthreads();  // before next lc overwrites stg
  }
}

// ---------------------------------------------------------------------------
// Kernel 2: per-i NT GEMM sim[j,c] = sum_l (xs[j,l]*m[i,l]) * ts[c,l], fused
// log-softmax over c + label-weighted diagonal pick, atomicAdd scalar loss.
// Mask applied by AND-ing A staging chunks with 0xFFFF/0x0000 ushorts (m in
// {0,1} -> exact).  1-D grid with bijective XCD remap: all 4 jt-blocks of a
// query i land on the same XCD -> B panel (128KB) fetched once per i.
// rule #20: no runtime indexing into acc[][] (diag pick = predicated select).
// ---------------------------------------------------------------------------
__global__ __launch_bounds__(256, 2) void gemm_lse(
    const unsigned short* __restrict__ xsT,
    const unsigned short* __restrict__ tsT,
    const int* __restrict__ mask,
    const int* __restrict__ label_mat,
    float* __restrict__ out)
{
  // XCD-aware decode: XCD(n) ~ n%8; give all 4 jt of one i the same residue.
  const int n  = blockIdx.x;
  const int g  = n & 7;
  const int q  = n >> 3;
  const int i  = ((q >> 2) << 3) + g;
  const int jt = q & 3;
  const int t  = threadIdx.x;
  const int w  = t >> 6;
  const int lane = t & 63;

  __shared__ __align__(16) unsigned char As[64 * 128];    // [64 j][64 l] bf16, swizzled
  __shared__ __align__(16) unsigned char Bs[256 * 128];   // [256 c][64 l] bf16, swizzled
  __shared__ __align__(16) unsigned short s_mask[NL];     // 0xFFFF / 0x0000 per l
  __shared__ float s_rmax[4][64];
  __shared__ float s_rsum[4][64];
  __shared__ float s_diag[64];

  const unsigned short* Ag = xsT + ((size_t)i * NB + jt * 64) * NL;  // rows j
  const unsigned short* Bg = tsT + (size_t)i * NB * NL;              // rows c

  const int srow = t >> 3;       // staging row base
  const int sch  = t & 7;        // staging 16B-chunk within row

  // mask row i -> AND-mask in LDS (coalesced 1 int/thread)
  s_mask[t] = (mask[i * NL + t] > 0) ? (unsigned short)0xFFFFu : (unsigned short)0u;

  f32x4 acc[4][4];
  #pragma unroll
  for (int a = 0; a < 4; ++a)
    #pragma unroll
    for (int cc = 0; cc < 4; ++cc) acc[a][cc] = f32x4{0.f, 0.f, 0.f, 0.f};

  u32x4 areg[2], breg[8];

  // prologue: load chunk 0
  #pragma unroll
  for (int r = 0; r < 2; ++r)
    areg[r] = *reinterpret_cast<const u32x4*>(Ag + (size_t)(srow + r * 32) * NL + sch * 8);
  #pragma unroll
  for (int r = 0; r < 8; ++r)
    breg[r] = *reinterpret_cast<const u32x4*>(Bg + (size_t)(srow + r * 32) * NL + sch * 8);

  __syncthreads();  // s_mask ready before first masked store

  #pragma unroll
  for (int kc = 0; kc < 4; ++kc) {
    // store staged chunk (XOR-swizzled); A chunks masked
    u32x4 mk = *reinterpret_cast<const u32x4*>(&s_mask[kc * 64 + sch * 8]);
    #pragma unroll
    for (int r = 0; r < 2; ++r) {
      int row = srow + r * 32;
      u32x4 a = areg[r];
      a.x &= mk.x; a.y &= mk.y; a.z &= mk.z; a.w &= mk.w;
      *reinterpret_cast<u32x4*>(&As[row * 128 + ((sch ^ (row & 7)) << 4)]) = a;
    }
    #pragma unroll
    for (int r = 0; r < 8; ++r) {
      int row = srow + r * 32;
      *reinterpret_cast<u32x4*>(&Bs[row * 128 + ((sch ^ (row & 7)) << 4)]) = breg[r];
    }
    __syncthreads();
    if (kc < 3) {
      const int kofs = (kc + 1) * 64;
      #pragma unroll
      for (int r = 0; r < 2; ++r)
        areg[r] = *reinterpret_cast<const u32x4*>(Ag + (size_t)(srow + r * 32) * NL + kofs + sch * 8);
      #pragma unroll
      for (int r = 0; r < 8; ++r)
        breg[r] = *reinterpret_cast<const u32x4*>(Bg + (size_t)(srow + r * 32) * NL + kofs + sch * 8);
    }
    #pragma unroll
    for (int kk = 0; kk < 2; ++kk) {
      const int co = kk * 4 + (lane >> 4);  // 16B chunk index within row
      bfrag8 af[4], bfr[4];
      #pragma unroll
      for (int jf = 0; jf < 4; ++jf) {
        int row = jf * 16 + (lane & 15);
        af[jf] = *reinterpret_cast<const bfrag8*>(&As[row * 128 + ((co ^ (row & 7)) << 4)]);
      }
      #pragma unroll
      for (int cf = 0; cf < 4; ++cf) {
        int row = w * 64 + cf * 16 + (lane & 15);
        bfr[cf] = *reinterpret_cast<const bfrag8*>(&Bs[row * 128 + ((co ^ (row & 7)) << 4)]);
      }
      #pragma unroll
      for (int jf = 0; jf < 4; ++jf)
        #pragma unroll
        for (int cf = 0; cf < 4; ++cf)
          acc[jf][cf] = __builtin_amdgcn_mfma_f32_16x16x32_bf16(
              af[jf], bfr[cf], acc[jf][cf], 0, 0, 0);
    }
    __syncthreads();
  }

  // ---- epilogue: logits = 100*sim; per-row (j) logsumexp over c; diag pick ----
  #pragma unroll
  for (int jf = 0; jf < 4; ++jf)
    #pragma unroll
    for (int cf = 0; cf < 4; ++cf) acc[jf][cf] *= SCALE;

  const int rg = (lane >> 4) << 2;  // this lane holds rows jf*16 + rg + reg

  #pragma unroll
  for (int jf = 0; jf < 4; ++jf) {
    #pragma unroll
    for (int reg = 0; reg < 4; ++reg) {
      float m = fmaxf(fmaxf(acc[jf][0][reg], acc[jf][1][reg]),
                      fmaxf(acc[jf][2][reg], acc[jf][3][reg]));
      #pragma unroll
      for (int off = 1; off < 16; off <<= 1) m = fmaxf(m, __shfl_xor(m, off, 64));
      if ((lane & 15) == 0) s_rmax[w][jf * 16 + rg + reg] = m;
    }
  }
  // diagonal element c == i: wave i>>6, frag (i>>4)&3, lanes lane&15 == i&15.
  // COMPILE-TIME indices only — predicated select over cf (rule #20).
  if (w == (i >> 6) && (lane & 15) == (i & 15)) {
    const int cfd = (i >> 4) & 3;
    #pragma unroll
    for (int jf = 0; jf < 4; ++jf) {
      #pragma unroll
      for (int reg = 0; reg < 4; ++reg) {
        float v = acc[jf][0][reg];
        #pragma unroll
        for (int cf = 1; cf < 4; ++cf)
          v = (cfd == cf) ? acc[jf][cf][reg] : v;
        s_diag[jf * 16 + rg + reg] = v;
      }
    }
  }
  __syncthreads();

  #pragma unroll
  for (int jf = 0; jf < 4; ++jf) {
    #pragma unroll
    for (int reg = 0; reg < 4; ++reg) {
      int row = jf * 16 + rg + reg;
      float gm = fmaxf(fmaxf(s_rmax[0][row], s_rmax[1][row]),
                       fmaxf(s_rmax[2][row], s_rmax[3][row]));
      float sE = 0.f;
      #pragma unroll
      for (int cf = 0; cf < 4; ++cf) sE += __expf(acc[jf][cf][reg] - gm);
      #pragma unroll
      for (int off = 1; off < 16; off <<= 1) sE += __shfl_xor(sE, off, 64);
      if ((lane & 15) == 0) s_rsum[w][row] = sE;
    }
  }
  __syncthreads();

  float contrib = 0.f;
  if (t < 64) {
    const int row = t;
    float gm = fmaxf(fmaxf(s_rmax[0][row], s_rmax[1][row]),
                     fmaxf(s_rmax[2][row], s_rmax[3][row]));
    float tot = s_rsum[0][row] + s_rsum[1][row] + s_rsum[2][row] + s_rsum[3][row];
    float lse = __logf(tot) + gm;
    float lbl = (float)label_mat[i * NB + jt * 64 + row];
    contrib = lbl * (s_diag[row] - lse);
  }
  #pragma unroll
  for (int off = 32; off >= 1; off >>= 1) contrib += __shfl_down(contrib, off, 64);
  if (t == 0) atomicAdd(out, contrib * (-1.0f / 256.0f));
}

extern "C" void kernel_launch(void* const* d_in, const int* in_sizes, int n_in,
                              void* d_out, int out_size, void* d_ws, size_t ws_size,
                              hipStream_t stream) {
  const float* x   = (const float*)d_in[0];
  const float* tgt = (const float*)d_in[1];
  const int* mask  = (const int*)d_in[2];
  // d_in[3] = query_labels (unused by the reference computation)
  const int* label_mat = (const int*)d_in[4];
  float* out = (float*)d_out;

  unsigned int* xsT = (unsigned int*)d_ws;                       // 32 MiB bf16 [i][j][l]
  unsigned int* tsT = xsT + (size_t)NB * NB * NL / 2;            // 32 MiB bf16 [i][c][l]

  hipMemsetAsync(out, 0, sizeof(float), stream);
  softmax_t<<<dim3(NB, 2), 1024, 0, stream>>>(x, tgt, xsT, tsT);
  gemm_lse<<<dim3(1024), 256, 0, stream>>>((const unsigned short*)xsT,
                                           (const unsigned short*)tsT,
                                           mask, label_mat, out);
}

// Round 5
// 75.982 us; speedup vs baseline: 2.2265x; 1.2085x over previous
//
#include <hip/hip_runtime.h>
#include <hip/hip_bf16.h>

#define NB 256      // batch == queries == classes
#define NL 256      // clips
#define SCALE 100.0f  // 1/TAU

typedef __attribute__((ext_vector_type(4))) unsigned int u32x4;
typedef __attribute__((ext_vector_type(8))) __bf16 bfrag8;
typedef __attribute__((ext_vector_type(4))) float f32x4;

union BU { bfrag8 f; u32x4 u; };

static __device__ __forceinline__ unsigned int pack2bf(float a, float b) {
  union { float f; unsigned int u; } ua, ub;
  ua.f = a; ub.f = b;
  unsigned int ra = (ua.u + 0x7FFFu + ((ua.u >> 16) & 1u)) >> 16;
  unsigned int rb = (ub.u + 0x7FFFu + ((ub.u >> 16) & 1u)) & 0xFFFF0000u;
  return ra | rb;
}

// ---------------------------------------------------------------------------
// Kernel 1: exp-transpose.  dst[i][b][l] = bf16(exp(src[b,l,i])) — NO
// normalization (row scales factor out of the GEMM; denominators are
// recomputed in the GEMM via ones-MFMA row/col sums).  Single pass: read
// 128MB once, write 64MB once.  LDS-staged transpose -> full-128B-line
// writes (8 lanes per row).
// ---------------------------------------------------------------------------
__global__ __launch_bounds__(1024, 2) void exp_t(
    const float* __restrict__ x, const float* __restrict__ tgt,
    unsigned int* __restrict__ xsT, unsigned int* __restrict__ tsT)
{
  const int b = blockIdx.x;
  const bool is_t = (blockIdx.y != 0);
  const int tid = threadIdx.x;
  const int i = tid & 255;
  const int h = tid >> 8;  // l-sixteenth group
  const float* src = (is_t ? tgt : x) + (size_t)b * (NL * NB) + i;
  unsigned int* dstb = (is_t ? tsT : xsT);  // u32-indexed, layout [i][b][l/2]

  __shared__ __align__(16) unsigned char stg[256 * 128];  // [i][64 l] bf16, swizzled

  const int r0 = tid >> 3;  // writer rows r0 and r0+128
  const int c  = tid & 7;   // writer 16B chunk within 128B row-segment

  for (int lc = 0; lc < 4; ++lc) {
    float v[16];
    #pragma unroll
    for (int k = 0; k < 16; ++k)
      v[k] = __expf(src[(size_t)(lc * 64 + h * 16 + k) * NB]);
    u32x4 p0, p1;
    p0.x = pack2bf(v[0], v[1]);   p0.y = pack2bf(v[2], v[3]);
    p0.z = pack2bf(v[4], v[5]);   p0.w = pack2bf(v[6], v[7]);
    p1.x = pack2bf(v[8], v[9]);   p1.y = pack2bf(v[10], v[11]);
    p1.z = pack2bf(v[12], v[13]); p1.w = pack2bf(v[14], v[15]);
    // stage: row i, chunks h*2, h*2+1, XOR-swizzled by i&7
    *reinterpret_cast<u32x4*>(&stg[i * 128 + (((h * 2 + 0) ^ (i & 7)) << 4)]) = p0;
    *reinterpret_cast<u32x4*>(&stg[i * 128 + (((h * 2 + 1) ^ (i & 7)) << 4)]) = p1;
    __syncthreads();
    // write out: 256 rows x 128B; 8 lanes per row -> one full line per group
    u32x4 q0 = *reinterpret_cast<const u32x4*>(&stg[r0 * 128 + ((c ^ (r0 & 7)) << 4)]);
    u32x4 q1 = *reinterpret_cast<const u32x4*>(&stg[(r0 + 128) * 128 + ((c ^ (r0 & 7)) << 4)]);
    *reinterpret_cast<u32x4*>(dstb + ((size_t)r0 * 256 + b) * 128 + lc * 32 + c * 4) = q0;
    *reinterpret_cast<u32x4*>(dstb + ((size_t)(r0 + 128) * 256 + b) * 128 + lc * 32 + c * 4) = q1;
    __syncthreads();  // before next lc overwrites stg
  }
}

// ---------------------------------------------------------------------------
// Kernel 2: per-i NT GEMM on UNNORMALIZED exp values:
//   raw[j,c]    = sum_l (ex[j,l] & m[l]) * et[c,l]        (masked sim-MFMAs)
//   rowsum[j]   = sum_l ex[j,l]      via MFMA(af, ones)   (unmasked)
//   colsum[c]   = sum_l et[c,l]      via MFMA(ones, bfr)  (unmasked)
//   logits[j,c] = SCALE * raw * rcp(rowsum[j]) * rcp(colsum[c])
// then fused log-softmax over c + label-weighted diag pick -> atomicAdd.
// Mask applied at REGISTER level (af & mask_frag) so LDS tiles stay unmasked
// for the sum-MFMAs.  rule #20: all acc indexing compile-time.
// ---------------------------------------------------------------------------
__global__ __launch_bounds__(256, 2) void gemm_lse(
    const unsigned short* __restrict__ xsT,
    const unsigned short* __restrict__ tsT,
    const int* __restrict__ mask,
    const int* __restrict__ label_mat,
    float* __restrict__ out)
{
  // XCD-aware decode: all 4 jt-blocks of one i share an XCD residue.
  const int n  = blockIdx.x;
  const int g  = n & 7;
  const int q  = n >> 3;
  const int i  = ((q >> 2) << 3) + g;
  const int jt = q & 3;
  const int t  = threadIdx.x;
  const int w  = t >> 6;
  const int lane = t & 63;

  __shared__ __align__(16) unsigned char As[64 * 128];    // [64 j][64 l] bf16, swizzled
  __shared__ __align__(16) unsigned char Bs[256 * 128];   // [256 c][64 l] bf16, swizzled
  __shared__ __align__(16) unsigned short s_mask[NL];     // 0xFFFF / 0x0000 per l
  __shared__ float s_rmax[4][64];
  __shared__ float s_rsum[4][64];
  __shared__ float s_diag[64];

  const unsigned short* Ag = xsT + ((size_t)i * NB + jt * 64) * NL;  // rows j
  const unsigned short* Bg = tsT + (size_t)i * NB * NL;              // rows c

  const int srow = t >> 3;       // staging row base
  const int sch  = t & 7;        // staging 16B-chunk within row

  // mask row i -> AND-mask in LDS (coalesced 1 int/thread)
  s_mask[t] = (mask[i * NL + t] > 0) ? (unsigned short)0xFFFFu : (unsigned short)0u;

  BU onesbu;
  onesbu.u = u32x4{0x3F803F80u, 0x3F803F80u, 0x3F803F80u, 0x3F803F80u};
  const bfrag8 ones = onesbu.f;

  f32x4 acc[4][4], acc_as[4], acc_bs[4];
  #pragma unroll
  for (int a = 0; a < 4; ++a) {
    acc_as[a] = f32x4{0.f, 0.f, 0.f, 0.f};
    acc_bs[a] = f32x4{0.f, 0.f, 0.f, 0.f};
    #pragma unroll
    for (int cc = 0; cc < 4; ++cc) acc[a][cc] = f32x4{0.f, 0.f, 0.f, 0.f};
  }

  u32x4 areg[2], breg[8];

  // prologue: load chunk 0
  #pragma unroll
  for (int r = 0; r < 2; ++r)
    areg[r] = *reinterpret_cast<const u32x4*>(Ag + (size_t)(srow + r * 32) * NL + sch * 8);
  #pragma unroll
  for (int r = 0; r < 8; ++r)
    breg[r] = *reinterpret_cast<const u32x4*>(Bg + (size_t)(srow + r * 32) * NL + sch * 8);

  __syncthreads();  // s_mask ready before MFMA section reads it

  #pragma unroll
  for (int kc = 0; kc < 4; ++kc) {
    // store staged chunk (XOR-swizzled), UNMASKED both sides
    #pragma unroll
    for (int r = 0; r < 2; ++r) {
      int row = srow + r * 32;
      *reinterpret_cast<u32x4*>(&As[row * 128 + ((sch ^ (row & 7)) << 4)]) = areg[r];
    }
    #pragma unroll
    for (int r = 0; r < 8; ++r) {
      int row = srow + r * 32;
      *reinterpret_cast<u32x4*>(&Bs[row * 128 + ((sch ^ (row & 7)) << 4)]) = breg[r];
    }
    __syncthreads();
    if (kc < 3) {
      const int kofs = (kc + 1) * 64;
      #pragma unroll
      for (int r = 0; r < 2; ++r)
        areg[r] = *reinterpret_cast<const u32x4*>(Ag + (size_t)(srow + r * 32) * NL + kofs + sch * 8);
      #pragma unroll
      for (int r = 0; r < 8; ++r)
        breg[r] = *reinterpret_cast<const u32x4*>(Bg + (size_t)(srow + r * 32) * NL + kofs + sch * 8);
    }
    #pragma unroll
    for (int kk = 0; kk < 2; ++kk) {
      const int co = kk * 4 + (lane >> 4);  // 16B chunk index within row
      bfrag8 af[4], bfr[4];
      #pragma unroll
      for (int jf = 0; jf < 4; ++jf) {
        int row = jf * 16 + (lane & 15);
        af[jf] = *reinterpret_cast<const bfrag8*>(&As[row * 128 + ((co ^ (row & 7)) << 4)]);
      }
      #pragma unroll
      for (int cf = 0; cf < 4; ++cf) {
        int row = w * 64 + cf * 16 + (lane & 15);
        bfr[cf] = *reinterpret_cast<const bfrag8*>(&Bs[row * 128 + ((co ^ (row & 7)) << 4)]);
      }
      // mask fragment for this frag's k-positions (broadcast read)
      u32x4 mk = *reinterpret_cast<const u32x4*>(
          &s_mask[kc * 64 + kk * 32 + ((lane >> 4) << 3)]);
      #pragma unroll
      for (int jf = 0; jf < 4; ++jf) {
        BU am; am.f = af[jf]; am.u &= mk;
        #pragma unroll
        for (int cf = 0; cf < 4; ++cf)
          acc[jf][cf] = __builtin_amdgcn_mfma_f32_16x16x32_bf16(
              am.f, bfr[cf], acc[jf][cf], 0, 0, 0);
        acc_as[jf] = __builtin_amdgcn_mfma_f32_16x16x32_bf16(
            af[jf], ones, acc_as[jf], 0, 0, 0);   // unmasked row sums
      }
      #pragma unroll
      for (int cf = 0; cf < 4; ++cf)
        acc_bs[cf] = __builtin_amdgcn_mfma_f32_16x16x32_bf16(
            ones, bfr[cf], acc_bs[cf], 0, 0, 0);  // unmasked col sums
    }
    __syncthreads();
  }

  // ---- epilogue: logits = SCALE * raw * invx[row] * invt[col] ----
  float ixv[4][4];
  #pragma unroll
  for (int jf = 0; jf < 4; ++jf)
    #pragma unroll
    for (int reg = 0; reg < 4; ++reg)
      ixv[jf][reg] = __builtin_amdgcn_rcpf(acc_as[jf][reg]) * SCALE;
  float itv[4];
  #pragma unroll
  for (int cf = 0; cf < 4; ++cf)
    itv[cf] = __builtin_amdgcn_rcpf(acc_bs[cf][0]);
  #pragma unroll
  for (int jf = 0; jf < 4; ++jf)
    #pragma unroll
    for (int cf = 0; cf < 4; ++cf)
      #pragma unroll
      for (int reg = 0; reg < 4; ++reg)
        acc[jf][cf][reg] *= ixv[jf][reg] * itv[cf];

  const int rg = (lane >> 4) << 2;  // this lane holds rows jf*16 + rg + reg

  #pragma unroll
  for (int jf = 0; jf < 4; ++jf) {
    #pragma unroll
    for (int reg = 0; reg < 4; ++reg) {
      float m = fmaxf(fmaxf(acc[jf][0][reg], acc[jf][1][reg]),
                      fmaxf(acc[jf][2][reg], acc[jf][3][reg]));
      #pragma unroll
      for (int off = 1; off < 16; off <<= 1) m = fmaxf(m, __shfl_xor(m, off, 64));
      if ((lane & 15) == 0) s_rmax[w][jf * 16 + rg + reg] = m;
    }
  }
  // diagonal element c == i: wave i>>6, frag (i>>4)&3, lanes lane&15 == i&15.
  // COMPILE-TIME indices only — predicated select over cf (rule #20).
  if (w == (i >> 6) && (lane & 15) == (i & 15)) {
    const int cfd = (i >> 4) & 3;
    #pragma unroll
    for (int jf = 0; jf < 4; ++jf) {
      #pragma unroll
      for (int reg = 0; reg < 4; ++reg) {
        float v = acc[jf][0][reg];
        #pragma unroll
        for (int cf = 1; cf < 4; ++cf)
          v = (cfd == cf) ? acc[jf][cf][reg] : v;
        s_diag[jf * 16 + rg + reg] = v;
      }
    }
  }
  __syncthreads();

  #pragma unroll
  for (int jf = 0; jf < 4; ++jf) {
    #pragma unroll
    for (int reg = 0; reg < 4; ++reg) {
      int row = jf * 16 + rg + reg;
      float gm = fmaxf(fmaxf(s_rmax[0][row], s_rmax[1][row]),
                       fmaxf(s_rmax[2][row], s_rmax[3][row]));
      float sE = 0.f;
      #pragma unroll
      for (int cf = 0; cf < 4; ++cf) sE += __expf(acc[jf][cf][reg] - gm);
      #pragma unroll
      for (int off = 1; off < 16; off <<= 1) sE += __shfl_xor(sE, off, 64);
      if ((lane & 15) == 0) s_rsum[w][row] = sE;
    }
  }
  __syncthreads();

  float contrib = 0.f;
  if (t < 64) {
    const int row = t;
    float gm = fmaxf(fmaxf(s_rmax[0][row], s_rmax[1][row]),
                     fmaxf(s_rmax[2][row], s_rmax[3][row]));
    float tot = s_rsum[0][row] + s_rsum[1][row] + s_rsum[2][row] + s_rsum[3][row];
    float lse = __logf(tot) + gm;
    float lbl = (float)label_mat[i * NB + jt * 64 + row];
    contrib = lbl * (s_diag[row] - lse);
  }
  #pragma unroll
  for (int off = 32; off >= 1; off >>= 1) contrib += __shfl_down(contrib, off, 64);
  if (t == 0) atomicAdd(out, contrib * (-1.0f / 256.0f));
}

extern "C" void kernel_launch(void* const* d_in, const int* in_sizes, int n_in,
                              void* d_out, int out_size, void* d_ws, size_t ws_size,
                              hipStream_t stream) {
  const float* x   = (const float*)d_in[0];
  const float* tgt = (const float*)d_in[1];
  const int* mask  = (const int*)d_in[2];
  // d_in[3] = query_labels (unused by the reference computation)
  const int* label_mat = (const int*)d_in[4];
  float* out = (float*)d_out;

  unsigned int* xsT = (unsigned int*)d_ws;                       // 32 MiB bf16 [i][j][l]
  unsigned int* tsT = xsT + (size_t)NB * NB * NL / 2;            // 32 MiB bf16 [i][c][l]

  hipMemsetAsync(out, 0, sizeof(float), stream);
  exp_t<<<dim3(NB, 2), 1024, 0, stream>>>(x, tgt, xsT, tsT);
  gemm_lse<<<dim3(1024), 256, 0, stream>>>((const unsigned short*)xsT,
                                           (const unsigned short*)tsT,
                                           mask, label_mat, out);
}

// Round 6
// 74.907 us; speedup vs baseline: 2.2584x; 1.0144x over previous
//
#include <hip/hip_runtime.h>
#include <hip/hip_bf16.h>

#define NB 256      // batch == queries == classes
#define NL 256      // clips
#define SCALE 100.0f  // 1/TAU

typedef __attribute__((ext_vector_type(4))) unsigned int u32x4;
typedef __attribute__((ext_vector_type(8))) __bf16 bfrag8;
typedef __attribute__((ext_vector_type(4))) float f32x4;

union BU { bfrag8 f; u32x4 u; };

static __device__ __forceinline__ unsigned int pack2bf(float a, float b) {
  union { float f; unsigned int u; } ua, ub;
  ua.f = a; ub.f = b;
  unsigned int ra = (ua.u + 0x7FFFu + ((ua.u >> 16) & 1u)) >> 16;
  unsigned int rb = (ub.u + 0x7FFFu + ((ub.u >> 16) & 1u)) & 0xFFFF0000u;
  return ra | rb;
}

// ---------------------------------------------------------------------------
// Kernel 1: exp-transpose.  dst[i][b][l] = bf16(exp(src[b,l,i])), no
// normalization (denominators recomputed in the GEMM via ones-MFMA).
// Round-6 change: f32x4 loads across i (16B/lane, 4 batched per round) —
// rounds 1-5's scalar-4B pattern plateaued at 2.3 TB/s with VGPR=16 (compiler
// serialized the load->exp chain).  LDS staging double-buffered (one barrier
// per round).  Writer rows stride 4/lane -> intrinsic bank aliasing; chunk
// swizzle ^(row&7)^((row>>3)&7) spreads it to ~4-8-way.  Reader/global-write
// pattern unchanged (full 128B lines, was conflict-free).
// ---------------------------------------------------------------------------
__global__ __launch_bounds__(1024, 2) void exp_t(
    const float* __restrict__ x, const float* __restrict__ tgt,
    unsigned int* __restrict__ xsT, unsigned int* __restrict__ tsT)
{
  const int b = blockIdx.x;
  const bool is_t = (blockIdx.y != 0);
  const int tid = threadIdx.x;
  const int i4 = tid & 63;   // float4 index across i  (i = 4*i4 .. 4*i4+3)
  const int g  = tid >> 6;   // l-group: 16 groups x 4 l per round
  const f32x4* src4 = reinterpret_cast<const f32x4*>(
      (is_t ? tgt : x) + (size_t)b * (NL * NB));
  unsigned int* dstb = (is_t ? tsT : xsT);  // u32 units, layout [i][b][l/2]

  __shared__ __align__(16) unsigned char stg[2][256 * 128];  // double-buffered

  const int r0 = tid >> 3;  // reader rows r0, r0+128
  const int c  = tid & 7;   // reader 16B chunk

  #pragma unroll
  for (int lc = 0; lc < 4; ++lc) {
    unsigned char* sb = stg[lc & 1];
    // batched 16B loads: 4 l's x 4 i's per thread
    f32x4 r[4];
    #pragma unroll
    for (int k = 0; k < 4; ++k)
      r[k] = src4[(size_t)(lc * 64 + g * 4 + k) * 64 + i4];
    #pragma unroll
    for (int ii = 0; ii < 4; ++ii) {
      const int row = i4 * 4 + ii;
      unsigned int lo = pack2bf(__expf(r[0][ii]), __expf(r[1][ii]));
      unsigned int hi = pack2bf(__expf(r[2][ii]), __expf(r[3][ii]));
      // 8B slot g of row's 128B: 16B chunk g>>1 (swizzled), inner half (g&1)
      const int ch = (g >> 1) ^ (row & 7) ^ ((row >> 3) & 7);
      unsigned int* p = reinterpret_cast<unsigned int*>(
          &sb[row * 128 + (ch << 4) + (g & 1) * 8]);
      p[0] = lo; p[1] = hi;
    }
    __syncthreads();
    // read back full 128B lines: 8 lanes per row
    const int ch0 = c ^ (r0 & 7) ^ ((r0 >> 3) & 7);
    u32x4 q0 = *reinterpret_cast<const u32x4*>(&sb[r0 * 128 + (ch0 << 4)]);
    u32x4 q1 = *reinterpret_cast<const u32x4*>(&sb[(r0 + 128) * 128 + (ch0 << 4)]);
    *reinterpret_cast<u32x4*>(dstb + ((size_t)r0 * 256 + b) * 128 + lc * 32 + c * 4) = q0;
    *reinterpret_cast<u32x4*>(dstb + ((size_t)(r0 + 128) * 256 + b) * 128 + lc * 32 + c * 4) = q1;
    // no trailing barrier: next round writes the other buffer; the barrier of
    // round lc+1 orders those writes after every wave's reads of this round.
  }
}

// ---------------------------------------------------------------------------
// Kernel 2: per-i NT GEMM on UNNORMALIZED exp values:
//   raw[j,c]  = sum_l (ex[j,l] & m[l]) * et[c,l]        (masked sim-MFMAs)
//   rowsum[j] = sum_l ex[j,l]      via MFMA(af, ones)
//   colsum[c] = sum_l et[c,l]      via MFMA(ones, bfr)
//   logits    = SCALE * raw * rcp(rowsum) * rcp(colsum)
// + fused log-softmax over c + label-weighted diag pick -> atomicAdd.
// Round-6 change: 2-deep register prefetch pipeline — at 2 blocks/CU (VGPR+
// AGPR ~230/wave is the floor) the 1-deep pipeline exposed a full L3 latency
// at every vmcnt-before-store (MfmaUtil 8%).  Now each store consumes loads
// issued two MFMA phases (~2.5k cy) earlier.  rule #20: acc indexing static.
// ---------------------------------------------------------------------------
__global__ __launch_bounds__(256, 2) void gemm_lse(
    const unsigned short* __restrict__ xsT,
    const unsigned short* __restrict__ tsT,
    const int* __restrict__ mask,
    const int* __restrict__ label_mat,
    float* __restrict__ out)
{
  // XCD-aware decode: all 4 jt-blocks of one i share an XCD residue.
  const int n  = blockIdx.x;
  const int g  = n & 7;
  const int q  = n >> 3;
  const int i  = ((q >> 2) << 3) + g;
  const int jt = q & 3;
  const int t  = threadIdx.x;
  const int w  = t >> 6;
  const int lane = t & 63;

  __shared__ __align__(16) unsigned char As[64 * 128];    // [64 j][64 l] bf16, swizzled
  __shared__ __align__(16) unsigned char Bs[256 * 128];   // [256 c][64 l] bf16, swizzled
  __shared__ __align__(16) unsigned short s_mask[NL];     // 0xFFFF / 0x0000 per l
  __shared__ float s_rmax[4][64];
  __shared__ float s_rsum[4][64];
  __shared__ float s_diag[64];

  const unsigned short* Ag = xsT + ((size_t)i * NB + jt * 64) * NL;  // rows j
  const unsigned short* Bg = tsT + (size_t)i * NB * NL;              // rows c

  const int srow = t >> 3;       // staging row base
  const int sch  = t & 7;        // staging 16B-chunk within row

  // mask row i -> AND-mask in LDS (coalesced 1 int/thread)
  s_mask[t] = (mask[i * NL + t] > 0) ? (unsigned short)0xFFFFu : (unsigned short)0u;

  BU onesbu;
  onesbu.u = u32x4{0x3F803F80u, 0x3F803F80u, 0x3F803F80u, 0x3F803F80u};
  const bfrag8 ones = onesbu.f;

  f32x4 acc[4][4], acc_as[4], acc_bs[4];
  #pragma unroll
  for (int a = 0; a < 4; ++a) {
    acc_as[a] = f32x4{0.f, 0.f, 0.f, 0.f};
    acc_bs[a] = f32x4{0.f, 0.f, 0.f, 0.f};
    #pragma unroll
    for (int cc = 0; cc < 4; ++cc) acc[a][cc] = f32x4{0.f, 0.f, 0.f, 0.f};
  }

  u32x4 a0[2], b0[8], a1[2], b1[8];

  auto load_set = [&](u32x4 (&ar)[2], u32x4 (&br)[8], int kc) {
    const int kofs = kc * 64;
    #pragma unroll
    for (int r = 0; r < 2; ++r)
      ar[r] = *reinterpret_cast<const u32x4*>(
          Ag + (size_t)(srow + r * 32) * NL + kofs + sch * 8);
    #pragma unroll
    for (int r = 0; r < 8; ++r)
      br[r] = *reinterpret_cast<const u32x4*>(
          Bg + (size_t)(srow + r * 32) * NL + kofs + sch * 8);
  };
  auto store_set = [&](u32x4 (&ar)[2], u32x4 (&br)[8]) {
    #pragma unroll
    for (int r = 0; r < 2; ++r) {
      int row = srow + r * 32;
      *reinterpret_cast<u32x4*>(&As[row * 128 + ((sch ^ (row & 7)) << 4)]) = ar[r];
    }
    #pragma unroll
    for (int r = 0; r < 8; ++r) {
      int row = srow + r * 32;
      *reinterpret_cast<u32x4*>(&Bs[row * 128 + ((sch ^ (row & 7)) << 4)]) = br[r];
    }
  };
  auto mfma_phase = [&](int kc) {
    #pragma unroll
    for (int kk = 0; kk < 2; ++kk) {
      const int co = kk * 4 + (lane >> 4);  // 16B chunk index within row
      bfrag8 af[4], bfr[4];
      #pragma unroll
      for (int jf = 0; jf < 4; ++jf) {
        int row = jf * 16 + (lane & 15);
        af[jf] = *reinterpret_cast<const bfrag8*>(
            &As[row * 128 + ((co ^ (row & 7)) << 4)]);
      }
      #pragma unroll
      for (int cf = 0; cf < 4; ++cf) {
        int row = w * 64 + cf * 16 + (lane & 15);
        bfr[cf] = *reinterpret_cast<const bfrag8*>(
            &Bs[row * 128 + ((co ^ (row & 7)) << 4)]);
      }
      u32x4 mk = *reinterpret_cast<const u32x4*>(
          &s_mask[kc * 64 + kk * 32 + ((lane >> 4) << 3)]);
      #pragma unroll
      for (int jf = 0; jf < 4; ++jf) {
        BU am; am.f = af[jf]; am.u &= mk;
        #pragma unroll
        for (int cf = 0; cf < 4; ++cf)
          acc[jf][cf] = __builtin_amdgcn_mfma_f32_16x16x32_bf16(
              am.f, bfr[cf], acc[jf][cf], 0, 0, 0);
        acc_as[jf] = __builtin_amdgcn_mfma_f32_16x16x32_bf16(
            af[jf], ones, acc_as[jf], 0, 0, 0);   // unmasked row sums
      }
      #pragma unroll
      for (int cf = 0; cf < 4; ++cf)
        acc_bs[cf] = __builtin_amdgcn_mfma_f32_16x16x32_bf16(
            ones, bfr[cf], acc_bs[cf], 0, 0, 0);  // unmasked col sums
    }
  };

  // ---- 2-deep pipelined K loop (chunks 0..3, LDS single-buffered) ----
  load_set(a0, b0, 0);
  load_set(a1, b1, 1);
  store_set(a0, b0);                       // waits only a0/b0 (vmcnt(10))
  __syncthreads();                         // also covers s_mask
  load_set(a0, b0, 2);
  mfma_phase(0);
  __syncthreads();
  store_set(a1, b1);
  __syncthreads();
  load_set(a1, b1, 3);
  mfma_phase(1);
  __syncthreads();
  store_set(a0, b0);                       // chunk-2 loads: 2 phases old
  __syncthreads();
  mfma_phase(2);
  __syncthreads();
  store_set(a1, b1);                       // chunk-3 loads: 2 phases old
  __syncthreads();
  mfma_phase(3);

  // ---- epilogue: logits = SCALE * raw * invx[row] * invt[col] ----
  float ixv[4][4];
  #pragma unroll
  for (int jf = 0; jf < 4; ++jf)
    #pragma unroll
    for (int reg = 0; reg < 4; ++reg)
      ixv[jf][reg] = __builtin_amdgcn_rcpf(acc_as[jf][reg]) * SCALE;
  float itv[4];
  #pragma unroll
  for (int cf = 0; cf < 4; ++cf)
    itv[cf] = __builtin_amdgcn_rcpf(acc_bs[cf][0]);
  #pragma unroll
  for (int jf = 0; jf < 4; ++jf)
    #pragma unroll
    for (int cf = 0; cf < 4; ++cf)
      #pragma unroll
      for (int reg = 0; reg < 4; ++reg)
        acc[jf][cf][reg] *= ixv[jf][reg] * itv[cf];

  const int rg = (lane >> 4) << 2;  // this lane holds rows jf*16 + rg + reg

  #pragma unroll
  for (int jf = 0; jf < 4; ++jf) {
    #pragma unroll
    for (int reg = 0; reg < 4; ++reg) {
      float m = fmaxf(fmaxf(acc[jf][0][reg], acc[jf][1][reg]),
                      fmaxf(acc[jf][2][reg], acc[jf][3][reg]));
      #pragma unroll
      for (int off = 1; off < 16; off <<= 1) m = fmaxf(m, __shfl_xor(m, off, 64));
      if ((lane & 15) == 0) s_rmax[w][jf * 16 + rg + reg] = m;
    }
  }
  // diagonal element c == i: wave i>>6, frag (i>>4)&3, lanes lane&15 == i&15.
  // COMPILE-TIME indices only — predicated select over cf (rule #20).
  if (w == (i >> 6) && (lane & 15) == (i & 15)) {
    const int cfd = (i >> 4) & 3;
    #pragma unroll
    for (int jf = 0; jf < 4; ++jf) {
      #pragma unroll
      for (int reg = 0; reg < 4; ++reg) {
        float v = acc[jf][0][reg];
        #pragma unroll
        for (int cf = 1; cf < 4; ++cf)
          v = (cfd == cf) ? acc[jf][cf][reg] : v;
        s_diag[jf * 16 + rg + reg] = v;
      }
    }
  }
  __syncthreads();

  #pragma unroll
  for (int jf = 0; jf < 4; ++jf) {
    #pragma unroll
    for (int reg = 0; reg < 4; ++reg) {
      int row = jf * 16 + rg + reg;
      float gm = fmaxf(fmaxf(s_rmax[0][row], s_rmax[1][row]),
                       fmaxf(s_rmax[2][row], s_rmax[3][row]));
      float sE = 0.f;
      #pragma unroll
      for (int cf = 0; cf < 4; ++cf) sE += __expf(acc[jf][cf][reg] - gm);
      #pragma unroll
      for (int off = 1; off < 16; off <<= 1) sE += __shfl_xor(sE, off, 64);
      if ((lane & 15) == 0) s_rsum[w][row] = sE;
    }
  }
  __syncthreads();

  float contrib = 0.f;
  if (t < 64) {
    const int row = t;
    float gm = fmaxf(fmaxf(s_rmax[0][row], s_rmax[1][row]),
                     fmaxf(s_rmax[2][row], s_rmax[3][row]));
    float tot = s_rsum[0][row] + s_rsum[1][row] + s_rsum[2][row] + s_rsum[3][row];
    float lse = __logf(tot) + gm;
    float lbl = (float)label_mat[i * NB + jt * 64 + row];
    contrib = lbl * (s_diag[row] - lse);
  }
  #pragma unroll
  for (int off = 32; off >= 1; off >>= 1) contrib += __shfl_down(contrib, off, 64);
  if (t == 0) atomicAdd(out, contrib * (-1.0f / 256.0f));
}

extern "C" void kernel_launch(void* const* d_in, const int* in_sizes, int n_in,
                              void* d_out, int out_size, void* d_ws, size_t ws_size,
                              hipStream_t stream) {
  const float* x   = (const float*)d_in[0];
  const float* tgt = (const float*)d_in[1];
  const int* mask  = (const int*)d_in[2];
  // d_in[3] = query_labels (unused by the reference computation)
  const int* label_mat = (const int*)d_in[4];
  float* out = (float*)d_out;

  unsigned int* xsT = (unsigned int*)d_ws;                       // 32 MiB bf16 [i][j][l]
  unsigned int* tsT = xsT + (size_t)NB * NB * NL / 2;            // 32 MiB bf16 [i][c][l]

  hipMemsetAsync(out, 0, sizeof(float), stream);
  exp_t<<<dim3(NB, 2), 1024, 0, stream>>>(x, tgt, xsT, tsT);
  gemm_lse<<<dim3(1024), 256, 0, stream>>>((const unsigned short*)xsT,
                                           (const unsigned short*)tsT,
                                           mask, label_mat, out);
}